// Round 6
// baseline (2344.172 us; speedup 1.0000x reference)
//
#include <hip/hip_runtime.h>

// VQ nearest-neighbor, two-pass:
//  pass1: single-product fp16 MFMA (Zh.Ch) approx scores + per-row top-2 + sound
//         error margin;  gather: certify winner / exact-rescore-2 / flag row;
//  rescue: exact fp32 re-scan of flagged rows (sound fallback, ~1% of rows).
// score(k) = csq[k] - 2*z.c_k  (monotone in distance; z_sq/sqrt dropped)

constexpr int Bn = 8192;
constexpr int Kn = 8192;
constexpr int Dn = 512;

using half8  = __attribute__((ext_vector_type(8)))  _Float16;
using f32x16 = __attribute__((ext_vector_type(16))) float;

// workspace layout (bytes), total 32MB
#define WS_CSQ   0u                    // 32KB fp32 csq[8192]
#define WS_ZSQ   (32u*1024u)           // 32KB fp32 zsq[8192]
#define WS_MAX   (64u*1024u)           // 4B   max csq (float bits, atomicMax int)
#define WS_CNT   (64u*1024u + 64u)     // 4B   worklist count
#define WS_WL    (96u*1024u)           // 32KB int wl[8192]
#define WS_PART  (1u*1024u*1024u)      // 4MB  float4 partials[8192][32]
#define WS_P2    (6u*1024u*1024u)      // 8MB  float2 partials2[8192][128]
#define WS_ZH    (16u*1024u*1024u)     // 8MB  fp16 h image of Z (frag-contiguous)
#define WS_CH    (24u*1024u*1024u)     // 8MB  fp16 h image of C (frag-contiguous)

typedef __attribute__((address_space(3))) void       as3_void;
typedef const __attribute__((address_space(1))) void as1_cvoid;

#define MFMA16 __builtin_amdgcn_mfma_f32_32x32x16_f16

// ---------------- prep: fp16 h images + row sumsq (exact fp32) ---------------
// one wave per row; lane covers cols [lane*8, lane*8+8)
__global__ __launch_bounds__(256) void prep_kernel(const float* __restrict__ Z,
                                                   const float* __restrict__ Cb,
                                                   char* __restrict__ ws) {
  const int w = threadIdx.x >> 6, lane = threadIdx.x & 63;
  const int rid = blockIdx.x * 4 + w;                 // 0..16383
  if (blockIdx.x == 0 && threadIdx.x == 0) *(int*)(ws + WS_CNT) = 0;
  const bool isZ = rid < Bn;
  const int r = isZ ? rid : rid - Bn;
  const float* src = (isZ ? Z : Cb) + (size_t)r * Dn + lane * 8;
  const float4 v0 = *reinterpret_cast<const float4*>(src);
  const float4 v1 = *reinterpret_cast<const float4*>(src + 4);
  const float f[8] = {v0.x, v0.y, v0.z, v0.w, v1.x, v1.y, v1.z, v1.w};
  float ss = 0.f;
  _Float16 h[8];
#pragma unroll
  for (int j = 0; j < 8; ++j) { ss += f[j] * f[j]; h[j] = (_Float16)f[j]; }
#pragma unroll
  for (int off = 32; off; off >>= 1) ss += __shfl_xor(ss, off);
  const half8 vh = {h[0], h[1], h[2], h[3], h[4], h[5], h[6], h[7]};
  const int kt = lane >> 1, kh = lane & 1;
  size_t chunk;
  char* img;
  if (isZ) {  // A-image: tile(rowblk,kt) 4KB = 4 frags x 1KB; frag grp = row-32-group
    const int rowblk = r >> 7, rloc = r & 127, grp = rloc >> 5, rr = rloc & 31;
    chunk = (size_t)(rowblk * 32 + kt) * 256 + grp * 64 + kh * 32 + rr;
    img = ws + WS_ZH;
  } else {    // B-image: tile(colblk,kt) 8KB = 8 frags x 1KB
    const int colblk = r >> 8, grp = (r >> 5) & 7, rr = r & 31;
    chunk = (size_t)(colblk * 32 + kt) * 512 + grp * 64 + kh * 32 + rr;
    img = ws + WS_CH;
  }
  *reinterpret_cast<half8*>(img + chunk * 16) = vh;
  if (lane == 0) {
    if (isZ) ((float*)(ws + WS_ZSQ))[r] = ss;
    else {
      ((float*)(ws + WS_CSQ))[r] = ss;
      atomicMax((int*)(ws + WS_MAX), __float_as_int(ss));  // ss > 0: int order = float order
    }
  }
}

// ---------------- pass1: h.h MFMA + per-lane top-2 ---------------------------
// grid = 64 rowblks * 16 splits = 1024, 256 thr (4 waves 2x2), 4 blocks/CU.
// Block: 128 rows x 512 cols (2 panels of 256), BK=16 -> 64 steps.
// B: LDS dbuf via global_load_lds (8KB/step); A: direct global->reg, prefetch 1.
// Stage issued AFTER the barrier: at next step's vmcnt(0) those loads are a
// full interval old -> drain is ~free (round-5 lesson).
__global__ __launch_bounds__(256, 4) void vq_pass1(const char* __restrict__ ws) {
  __shared__ uint4 lds4[1152];  // 18KB: B buf0 8K | B buf1 8K | csq slice 2K
  char* lds = (char*)lds4;
  const int t = threadIdx.x, lane = t & 63, w = t >> 6;
  const int wm = w >> 1, wn = w & 1;
  const int rowblk = blockIdx.x >> 4, split = blockIdx.x & 15;  // split%8 -> XCD
  const int r31 = lane & 31, kh = lane >> 5;
  const char* ZH = ws + WS_ZH;
  const char* CH = ws + WS_CH;
  float4* partials = (float4*)(ws + WS_PART);
  const size_t l16 = (size_t)lane * 16;

  float qs1[2][16], qs2[2][16];
  int qi1[2][16], qi2[2][16];
#pragma unroll
  for (int ms = 0; ms < 2; ++ms)
#pragma unroll
    for (int r = 0; r < 16; ++r) {
      qs1[ms][r] = 3e38f; qs2[ms][r] = 3e38f; qi1[ms][r] = 0; qi2[ms][r] = 0;
    }

  auto STAGE_B = [&](int v) {
    const size_t tile = (size_t)((split * 2 + (v >> 5)) * 32 + (v & 31));
    const char* s = CH + tile * 8192 + w * 2048 + l16;
    char* d = lds + (v & 1) * 8192 + w * 2048;
    __builtin_amdgcn_global_load_lds((as1_cvoid*)(s), (as3_void*)(d), 16, 0, 0);
    __builtin_amdgcn_global_load_lds((as1_cvoid*)(s + 1024), (as3_void*)(d + 1024), 16, 0, 0);
  };
  auto LOAD_A = [&](int v, half8& a0, half8& a1) {
    const char* s = ZH + (size_t)(rowblk * 32 + (v & 31)) * 4096 + (wm * 2) * 1024 + l16;
    a0 = *reinterpret_cast<const half8*>(s);
    a1 = *reinterpret_cast<const half8*>(s + 1024);
  };

  // prologue: csq slice (512 f32 = 2KB), B(0), A(0)
  if (w < 2)
    __builtin_amdgcn_global_load_lds(
        (as1_cvoid*)(ws + WS_CSQ + split * 2048 + w * 1024 + l16),
        (as3_void*)(lds + 16384 + w * 1024), 16, 0, 0);
  STAGE_B(0);
  half8 aE0, aE1, aO0, aO1;
  LOAD_A(0, aE0, aE1);

  for (int panel = 0; panel < 2; ++panel) {
    f32x16 acc[2][4] = {};
    for (int kt2 = 0; kt2 < 16; ++kt2) {
      const int u = panel * 32 + kt2 * 2;
      // ---- even step u (A in aE) ----
      asm volatile("s_waitcnt vmcnt(0)" ::: "memory");
      __builtin_amdgcn_s_barrier();
      asm volatile("" ::: "memory");
      half8 b0, b1, b2, b3;
      {
        const char* bb = lds + (u & 1) * 8192 + (wn * 4) * 1024 + l16;
        b0 = *reinterpret_cast<const half8*>(bb);
        b1 = *reinterpret_cast<const half8*>(bb + 1024);
        b2 = *reinterpret_cast<const half8*>(bb + 2048);
        b3 = *reinterpret_cast<const half8*>(bb + 3072);
      }
      STAGE_B(u + 1);            // u+1 <= 63 always on even step
      LOAD_A(u + 1, aO0, aO1);
      acc[0][0] = MFMA16(aE0, b0, acc[0][0], 0, 0, 0);
      acc[0][1] = MFMA16(aE0, b1, acc[0][1], 0, 0, 0);
      acc[0][2] = MFMA16(aE0, b2, acc[0][2], 0, 0, 0);
      acc[0][3] = MFMA16(aE0, b3, acc[0][3], 0, 0, 0);
      acc[1][0] = MFMA16(aE1, b0, acc[1][0], 0, 0, 0);
      acc[1][1] = MFMA16(aE1, b1, acc[1][1], 0, 0, 0);
      acc[1][2] = MFMA16(aE1, b2, acc[1][2], 0, 0, 0);
      acc[1][3] = MFMA16(aE1, b3, acc[1][3], 0, 0, 0);
      // ---- odd step u+1 (A in aO) ----
      asm volatile("s_waitcnt vmcnt(0)" ::: "memory");
      __builtin_amdgcn_s_barrier();
      asm volatile("" ::: "memory");
      {
        const char* bb = lds + ((u + 1) & 1) * 8192 + (wn * 4) * 1024 + l16;
        b0 = *reinterpret_cast<const half8*>(bb);
        b1 = *reinterpret_cast<const half8*>(bb + 1024);
        b2 = *reinterpret_cast<const half8*>(bb + 2048);
        b3 = *reinterpret_cast<const half8*>(bb + 3072);
      }
      if (u + 2 < 64) { STAGE_B(u + 2); LOAD_A(u + 2, aE0, aE1); }
      acc[0][0] = MFMA16(aO0, b0, acc[0][0], 0, 0, 0);
      acc[0][1] = MFMA16(aO0, b1, acc[0][1], 0, 0, 0);
      acc[0][2] = MFMA16(aO0, b2, acc[0][2], 0, 0, 0);
      acc[0][3] = MFMA16(aO0, b3, acc[0][3], 0, 0, 0);
      acc[1][0] = MFMA16(aO1, b0, acc[1][0], 0, 0, 0);
      acc[1][1] = MFMA16(aO1, b1, acc[1][1], 0, 0, 0);
      acc[1][2] = MFMA16(aO1, b2, acc[1][2], 0, 0, 0);
      acc[1][3] = MFMA16(aO1, b3, acc[1][3], 0, 0, 0);
    }
    // ---- fold panel into per-lane running top-2 (lane-local, no shuffles) ----
    const int colbase = (split * 2 + panel) * 256 + wn * 128 + r31;
    float csv[4];
#pragma unroll
    for (int ns = 0; ns < 4; ++ns)
      csv[ns] = *reinterpret_cast<const float*>(
          lds + 16384 + (panel * 256 + wn * 128 + ns * 32 + r31) * 4);
#pragma unroll
    for (int ms = 0; ms < 2; ++ms)
#pragma unroll
      for (int r = 0; r < 16; ++r) {
        float s1v = qs1[ms][r], s2v = qs2[ms][r];
        int i1v = qi1[ms][r], i2v = qi2[ms][r];
#pragma unroll
        for (int ns = 0; ns < 4; ++ns) {
          const float s = fmaf(-2.f, acc[ms][ns][r], csv[ns]);
          const int ni = colbase + ns * 32;
          if (s < s1v) { s2v = s1v; i2v = i1v; s1v = s; i1v = ni; }
          else if (s < s2v) { s2v = s; i2v = ni; }
        }
        qs1[ms][r] = s1v; qs2[ms][r] = s2v; qi1[ms][r] = i1v; qi2[ms][r] = i2v;
      }
  }

  // ---- endgame: butterfly-merge top-2 across the 32 column-lanes, write ----
#pragma unroll
  for (int ms = 0; ms < 2; ++ms)
#pragma unroll
    for (int r = 0; r < 16; ++r) {
      float s1v = qs1[ms][r], s2v = qs2[ms][r];
      int i1v = qi1[ms][r], i2v = qi2[ms][r];
#pragma unroll
      for (int off = 1; off <= 16; off <<= 1) {
        const float os1 = __shfl_xor(s1v, off); const int oi1 = __shfl_xor(i1v, off);
        const float os2 = __shfl_xor(s2v, off); const int oi2 = __shfl_xor(i2v, off);
        const bool aF = (s1v < os1) || (s1v == os1 && i1v < oi1);
        const float w2s = aF ? s2v : os2; const int w2i = aF ? i2v : oi2;
        const float l1s = aF ? os1 : s1v; const int l1i = aF ? oi1 : i1v;
        const bool b2 = (w2s < l1s) || (w2s == l1s && w2i < l1i);
        s1v = aF ? s1v : os1; i1v = aF ? i1v : oi1;
        s2v = b2 ? w2s : l1s; i2v = b2 ? w2i : l1i;
      }
      const int slot = ms * 16 + r;
      if (r31 == slot) {
        const int grow = rowblk * 128 + wm * 64 + ms * 32 + (r & 3) + 8 * (r >> 2) + 4 * kh;
        partials[grow * 32 + split * 2 + wn] = make_float4(s1v, (float)i1v, s2v, (float)i2v);
      }
    }
}

// ---------------- gather: certify / rescore-2 / flag -------------------------
// 1 wave per row. Sound: winner certain unless >=3 union entries within margin
// or some slot's s2 within margin (could hide an unseen 3rd).
__global__ __launch_bounds__(64) void gather_finalize(const float* __restrict__ Z,
                                                      const float* __restrict__ Cb,
                                                      char* __restrict__ ws,
                                                      float* __restrict__ zq,
                                                      float* __restrict__ idx_out) {
  const int row = blockIdx.x, l = threadIdx.x, l31 = l & 31;
  const float4* partials = (const float4*)(ws + WS_PART);
  const float4 q = partials[row * 32 + l31];
  float s1 = q.x;
  int i1 = (int)q.y;
#pragma unroll
  for (int off = 1; off <= 16; off <<= 1) {
    const float os = __shfl_xor(s1, off); const int oi = __shfl_xor(i1, off);
    if (os < s1 || (os == s1 && oi < i1)) { s1 = os; i1 = oi; }
  }
  const float zs = ((const float*)(ws + WS_ZSQ))[row];
  const float cmax = *(const float*)(ws + WS_MAX);
  // eps_pair <= 2*2*(2^-10 + 511*2^-24)*||z||*||c||max ~ 4.03e-3*sqrt(zs*cmax)
  const float thr = s1 + 5.0e-3f * sqrtf(zs * cmax) + 0.15f;
  int cnt = (q.x <= thr ? 1 : 0) + (q.z <= thr ? 1 : 0);
  int hide = (q.z <= thr) ? 1 : 0;
#pragma unroll
  for (int off = 1; off <= 16; off <<= 1) {
    cnt += __shfl_xor(cnt, off);
    hide |= __shfl_xor(hide, off);
  }
  if (cnt >= 3 || hide) {
    if (l == 0) {
      const int pos = atomicAdd((int*)(ws + WS_CNT), 1);
      if (pos < Bn) ((int*)(ws + WS_WL))[pos] = row;
    }
    return;  // rescue kernels write this row
  }
  // best candidate excluding the winner
  float e1 = ((int)q.y == i1) ? 3e38f : q.x; int e1i = (int)q.y;
  float e2 = ((int)q.w == i1) ? 3e38f : q.z; int e2i = (int)q.w;
  const bool p2b = (e2 < e1) || (e2 == e1 && e2i < e1i);
  float cs_ = p2b ? e2 : e1;
  int ci_ = p2b ? e2i : e1i;
#pragma unroll
  for (int off = 1; off <= 16; off <<= 1) {
    const float os = __shfl_xor(cs_, off); const int oi = __shfl_xor(ci_, off);
    if (os < cs_ || (os == cs_ && oi < ci_)) { cs_ = os; ci_ = oi; }
  }
  int winner = i1;
  if (cs_ <= thr) {  // exact fp32 rescore of the two candidates
    const float4 z0 = *reinterpret_cast<const float4*>(Z + (size_t)row * Dn + l * 8);
    const float4 z1 = *reinterpret_cast<const float4*>(Z + (size_t)row * Dn + l * 8 + 4);
    const float4 a0 = *reinterpret_cast<const float4*>(Cb + (size_t)i1 * Dn + l * 8);
    const float4 a1 = *reinterpret_cast<const float4*>(Cb + (size_t)i1 * Dn + l * 8 + 4);
    const float4 c0 = *reinterpret_cast<const float4*>(Cb + (size_t)ci_ * Dn + l * 8);
    const float4 c1 = *reinterpret_cast<const float4*>(Cb + (size_t)ci_ * Dn + l * 8 + 4);
    float pa = z0.x * a0.x + z0.y * a0.y + z0.z * a0.z + z0.w * a0.w +
               z1.x * a1.x + z1.y * a1.y + z1.z * a1.z + z1.w * a1.w;
    float pb = z0.x * c0.x + z0.y * c0.y + z0.z * c0.z + z0.w * c0.w +
               z1.x * c1.x + z1.y * c1.y + z1.z * c1.z + z1.w * c1.w;
#pragma unroll
    for (int off = 1; off <= 32; off <<= 1) {
      pa += __shfl_xor(pa, off);
      pb += __shfl_xor(pb, off);
    }
    const float* csq = (const float*)(ws + WS_CSQ);
    const float sa = csq[i1] - 2.f * pa;
    const float sb = csq[ci_] - 2.f * pb;
    if (sb < sa || (sb == sa && ci_ < i1)) winner = ci_;
  }
  const float4 o0 = *reinterpret_cast<const float4*>(Cb + (size_t)winner * Dn + l * 8);
  const float4 o1 = *reinterpret_cast<const float4*>(Cb + (size_t)winner * Dn + l * 8 + 4);
  *reinterpret_cast<float4*>(zq + (size_t)row * Dn + l * 8) = o0;
  *reinterpret_cast<float4*>(zq + (size_t)row * Dn + l * 8 + 4) = o1;
  if (l == 0) idx_out[row] = (float)winner;
}

// ---------------- rescue1: exact fp32 scores for flagged rows (64x64 tiles) --
__global__ __launch_bounds__(256) void rescue1(const float* __restrict__ Z,
                                               const float* __restrict__ Cb,
                                               char* __restrict__ ws) {
  const int cntRaw = *(const int*)(ws + WS_CNT);
  const int cnt = cntRaw > Bn ? Bn : cntRaw;
  if (cnt == 0) return;
  const int tiles_r = (cnt + 63) >> 6;
  const int total = tiles_r * 128;
  const int* wl = (const int*)(ws + WS_WL);
  const float* csq = (const float*)(ws + WS_CSQ);
  float2* p2 = (float2*)(ws + WS_P2);
  __shared__ float As[32][68];
  __shared__ float Bs[32][68];
  __shared__ int wlrows[64];
  const int t = threadIdx.x;
  const int tx = t & 15, ty = t >> 4;
  const int sr = t >> 3, sc = (t & 7) * 4;
  for (int tile = blockIdx.x; tile < total; tile += gridDim.x) {
    const int tr = tile >> 7, tc = tile & 127;
    __syncthreads();
    if (t < 64) {
      const int wi = tr * 64 + t;
      wlrows[t] = wl[wi < cnt ? wi : cnt - 1];
    }
    __syncthreads();
    float acc[4][4] = {};
    for (int k0 = 0; k0 < Dn; k0 += 32) {
#pragma unroll
      for (int rr = 0; rr < 2; ++rr) {
        const int m = sr + rr * 32;
        const float4 v = *reinterpret_cast<const float4*>(Z + (size_t)wlrows[m] * Dn + k0 + sc);
        As[sc + 0][m] = v.x; As[sc + 1][m] = v.y; As[sc + 2][m] = v.z; As[sc + 3][m] = v.w;
        const float4 u = *reinterpret_cast<const float4*>(Cb + (size_t)(tc * 64 + m) * Dn + k0 + sc);
        Bs[sc + 0][m] = u.x; Bs[sc + 1][m] = u.y; Bs[sc + 2][m] = u.z; Bs[sc + 3][m] = u.w;
      }
      __syncthreads();
#pragma unroll
      for (int k = 0; k < 32; ++k) {
        const float4 a = *reinterpret_cast<const float4*>(&As[k][ty * 4]);
        const float4 b = *reinterpret_cast<const float4*>(&Bs[k][tx * 4]);
        acc[0][0] += a.x * b.x; acc[0][1] += a.x * b.y; acc[0][2] += a.x * b.z; acc[0][3] += a.x * b.w;
        acc[1][0] += a.y * b.x; acc[1][1] += a.y * b.y; acc[1][2] += a.y * b.z; acc[1][3] += a.y * b.w;
        acc[2][0] += a.z * b.x; acc[2][1] += a.z * b.y; acc[2][2] += a.z * b.z; acc[2][3] += a.z * b.w;
        acc[3][0] += a.w * b.x; acc[3][1] += a.w * b.y; acc[3][2] += a.w * b.z; acc[3][3] += a.w * b.w;
      }
      __syncthreads();
    }
#pragma unroll
    for (int i = 0; i < 4; ++i) {
      float bsv = 3e38f;
      int bi = 0;
#pragma unroll
      for (int j = 0; j < 4; ++j) {
        const int n = tc * 64 + tx * 4 + j;
        const float s = csq[n] - 2.f * acc[i][j];
        if (s < bsv || (s == bsv && n < bi)) { bsv = s; bi = n; }
      }
#pragma unroll
      for (int off = 1; off <= 8; off <<= 1) {
        const float os = __shfl_xor(bsv, off); const int oi = __shfl_xor(bi, off);
        if (os < bsv || (os == bsv && oi < bi)) { bsv = os; bi = oi; }
      }
      if (tx == 0) p2[(size_t)(tr * 64 + ty * 4 + i) * 128 + tc] = make_float2(bsv, (float)bi);
    }
  }
}

// ---------------- rescue2: combine 128 col-tile minima + write ---------------
__global__ __launch_bounds__(64) void rescue2(const float* __restrict__ Cb,
                                              char* __restrict__ ws,
                                              float* __restrict__ zq,
                                              float* __restrict__ idx_out) {
  const int cntRaw = *(const int*)(ws + WS_CNT);
  const int cnt = cntRaw > Bn ? Bn : cntRaw;
  const int* wl = (const int*)(ws + WS_WL);
  const float2* p2 = (const float2*)(ws + WS_P2);
  const int l = threadIdx.x;
  for (int rr = blockIdx.x; rr < cnt; rr += gridDim.x) {
    const int row = wl[rr];
    const float2 e1 = p2[(size_t)rr * 128 + l];
    const float2 e2 = p2[(size_t)rr * 128 + 64 + l];
    float bs_ = e1.x;
    int bi_ = (int)e1.y;
    if (e2.x < bs_ || (e2.x == bs_ && (int)e2.y < bi_)) { bs_ = e2.x; bi_ = (int)e2.y; }
#pragma unroll
    for (int off = 1; off <= 32; off <<= 1) {
      const float os = __shfl_xor(bs_, off); const int oi = __shfl_xor(bi_, off);
      if (os < bs_ || (os == bs_ && oi < bi_)) { bs_ = os; bi_ = oi; }
    }
    const float4 c0 = *reinterpret_cast<const float4*>(Cb + (size_t)bi_ * Dn + l * 8);
    const float4 c1 = *reinterpret_cast<const float4*>(Cb + (size_t)bi_ * Dn + l * 8 + 4);
    *reinterpret_cast<float4*>(zq + (size_t)row * Dn + l * 8) = c0;
    *reinterpret_cast<float4*>(zq + (size_t)row * Dn + l * 8 + 4) = c1;
    if (l == 0) idx_out[row] = (float)bi_;
  }
}

extern "C" void kernel_launch(void* const* d_in, const int* in_sizes, int n_in,
                              void* d_out, int out_size, void* d_ws, size_t ws_size,
                              hipStream_t stream) {
  const float* Z = (const float*)d_in[0];  // [B, D]
  const float* C = (const float*)d_in[1];  // [K, D]
  float* out = (float*)d_out;              // [B*D] z_q then [B] indices
  char* ws = (char*)d_ws;                  // 32MB

  prep_kernel<<<4096, 256, 0, stream>>>(Z, C, ws);
  vq_pass1<<<1024, 256, 0, stream>>>(ws);
  gather_finalize<<<Bn, 64, 0, stream>>>(Z, C, ws, out, out + (size_t)Bn * Dn);
  rescue1<<<512, 256, 0, stream>>>(Z, C, ws);
  rescue2<<<256, 64, 0, stream>>>(C, ws, out, out + (size_t)Bn * Dn);
}

// Round 7
// 266.113 us; speedup vs baseline: 8.8089x; 8.8089x over previous
//
#include <hip/hip_runtime.h>

// VQ nearest-neighbor, two-pass, swapped-operand MFMA:
//  pass1: mfma(A=codebook_h, B=z_h) -> lane holds 32 codebook candidates for its
//         own z-row in acc regs; in-lane top-2 fold (no shuffles); csq baked into
//         a 33rd k-tile (-csq/2 split into 2 fp16 parts, z ext = 1,1).
//  gather: certify winner with sound margin / exact-rescore <=4 visible / flag;
//  rescue: exact fp32 re-scan of flagged rows.
// score(k) = csq[k] - 2*z.c_k = -2*acc  (argmin score == argmax acc)

constexpr int Bn = 8192;
constexpr int Kn = 8192;
constexpr int Dn = 512;

using half8  = __attribute__((ext_vector_type(8)))  _Float16;
using f32x16 = __attribute__((ext_vector_type(16))) float;

// workspace layout (bytes), ~28.6MB
#define WS_CSQ  0u
#define WS_ZSQ  (32u*1024u)
#define WS_MAX  (64u*1024u)
#define WS_CNT  (64u*1024u + 64u)
#define WS_WL   (96u*1024u)
#define WS_PART (1u*1024u*1024u)   // float4 partials[8192][64] = 8MB
#define WS_P2   WS_PART            // rescue p2 aliases PART (PART dead after gather)
#define WS_CIMG (10u*1024u*1024u)  // codebook h image: 64 cblk x 33 kt x 4KB = 8.65MB
#define WS_ZIMG (19u*1024u*1024u)  // z h image:        32 zblk x 33 kt x 8KB = 8.65MB

typedef __attribute__((address_space(3))) void       as3_void;
typedef const __attribute__((address_space(1))) void as1_cvoid;

#define MFMA16 __builtin_amdgcn_mfma_f32_32x32x16_f16

// Fragment-contiguous images: tile = blk*33 + kt; frag grp (32 rows) = 1KB;
// chunk(16B) = tile*frags*64... chunk = tileBase + grp*64 + kh*32 + rr,
// element: row = blkrow + grp*32 + rr, k = kt*16 + kh*8 + j.
// kt=32 is the extension tile: codebook rows carry {-csq/2 hi, lo, 0...},
// z rows carry {1, 1, 0...} -> acc accumulates cross - csq/2.

// ---------------- prep: h images + ext tile + row sumsq ----------------------
__global__ __launch_bounds__(256) void prep_kernel(const float* __restrict__ Z,
                                                   const float* __restrict__ Cb,
                                                   char* __restrict__ ws) {
  const int w = threadIdx.x >> 6, lane = threadIdx.x & 63;
  const int rid = blockIdx.x * 4 + w;  // 0..16383
  if (blockIdx.x == 0 && threadIdx.x == 0) *(int*)(ws + WS_CNT) = 0;
  const bool isZ = rid < Bn;
  const int r = isZ ? rid : rid - Bn;
  const float* src = (isZ ? Z : Cb) + (size_t)r * Dn + lane * 8;
  const float4 v0 = *reinterpret_cast<const float4*>(src);
  const float4 v1 = *reinterpret_cast<const float4*>(src + 4);
  const float f[8] = {v0.x, v0.y, v0.z, v0.w, v1.x, v1.y, v1.z, v1.w};
  float ss = 0.f;
  _Float16 h[8];
#pragma unroll
  for (int j = 0; j < 8; ++j) { ss += f[j] * f[j]; h[j] = (_Float16)f[j]; }
#pragma unroll
  for (int off = 32; off; off >>= 1) ss += __shfl_xor(ss, off);
  const half8 vh = {h[0], h[1], h[2], h[3], h[4], h[5], h[6], h[7]};
  const int kt = lane >> 1, kh = lane & 1;
  int grp, rr, tbase, fr;
  char* img;
  if (isZ) {
    grp = (r >> 5) & 7; rr = r & 31; tbase = (r >> 8) * 33; fr = 512;
    img = ws + WS_ZIMG;
  } else {
    grp = (r >> 5) & 3; rr = r & 31; tbase = (r >> 7) * 33; fr = 256;
    img = ws + WS_CIMG;
  }
  const size_t chunk = (size_t)(tbase + kt) * fr + grp * 64 + kh * 32 + rr;
  *reinterpret_cast<half8*>(img + chunk * 16) = vh;
  if (lane < 2) {  // ext tile (kt=32): lane0 -> kh=0 payload chunk, lane1 -> kh=1 zeros
    half8 ev = {0, 0, 0, 0, 0, 0, 0, 0};
    if (lane == 0) {
      if (isZ) { ev[0] = (_Float16)1.f; ev[1] = (_Float16)1.f; }
      else {
        const _Float16 hi = (_Float16)(-0.5f * ss);
        ev[0] = hi; ev[1] = (_Float16)(-0.5f * ss - (float)hi);
      }
    }
    const size_t ec = (size_t)(tbase + 32) * fr + grp * 64 + lane * 32 + rr;
    *reinterpret_cast<half8*>(img + ec * 16) = ev;
  }
  if (lane == 0) {
    if (isZ) ((float*)(ws + WS_ZSQ))[r] = ss;
    else {
      ((float*)(ws + WS_CSQ))[r] = ss;
      atomicMax((int*)(ws + WS_MAX), __float_as_int(ss));  // ss>0: int order == float order
    }
  }
}

// ---------------- pass1: swapped-operand MFMA + in-lane top-2 ----------------
// grid = 32 zblk * 16 splits = 512 blocks, 256 thr (4 waves: wm=cb-half, wn=z-half),
// 2 blocks/CU. Block: z 256 rows x codebook 512 (4 panels x 128), BK=16+ext.
// z staged to LDS (3 rotating 8KB bufs, counted vmcnt); codebook global->reg.
__global__ __launch_bounds__(256, 2) void vq_pass1(char* __restrict__ ws) {
  __shared__ uint4 lds4[1536];  // 24KB
  char* lds = (char*)lds4;
  const int t = threadIdx.x, lane = t & 63, w = t >> 6;
  const int wm = w >> 1, wn = w & 1;
  const int zblk = blockIdx.x >> 4, split = blockIdx.x & 15;  // split%8 -> XCD
  const int r31 = lane & 31, kh = lane >> 5;
  const char* CI = ws + WS_CIMG;
  const char* ZI = ws + WS_ZIMG;
  const size_t l16 = (size_t)lane * 16;
  const size_t zsrc = (size_t)zblk * 33 * 8192 + (size_t)w * 2048 + l16;
  const size_t abase = (size_t)(wm * 2) * 1024 + l16;

  float qs1[4], qs2[4];
  int qi1[4];
#pragma unroll
  for (int nb = 0; nb < 4; ++nb) { qs1[nb] = -3e38f; qs2[nb] = -3e38f; qi1[nb] = 0x7fffffff; }

  f32x16 acc[2][4] = {};
  half8 aA0, aA1, aB0, aB1;

  auto STAGE = [&](int kv, int bsel) {  // z tile depends only on kt
    const char* s = ZI + zsrc + (size_t)kv * 8192;
    char* d = lds + bsel * 8192 + w * 2048;
    __builtin_amdgcn_global_load_lds((as1_cvoid*)(s), (as3_void*)(d), 16, 0, 0);
    __builtin_amdgcn_global_load_lds((as1_cvoid*)(s + 1024), (as3_void*)(d + 1024), 16, 0, 0);
  };

  // prologue
  STAGE(0, 0);
  STAGE(1, 1);
  {
    const char* s = CI + (size_t)(split * 4 * 33 + 0) * 4096 + abase;
    aA0 = *reinterpret_cast<const half8*>(s);
    aA1 = *reinterpret_cast<const half8*>(s + 1024);
  }
  asm volatile("s_waitcnt vmcnt(0)" ::: "memory");
  __builtin_amdgcn_s_barrier();

  int kt = 0, panel = 0, cur = 0, stg = 2;
#pragma unroll 2
  for (int u = 0; u < 132; ++u) {
    int k1 = kt + 1, p1 = panel;
    if (k1 == 33) { k1 = 0; ++p1; }
    int k2 = kt + 2, p2v = panel;
    if (k2 >= 33) { k2 -= 33; ++p2v; }
    if (u + 1 < 132) {  // codebook frags for next step -> alternate reg set
      const char* s = CI + (size_t)((split * 4 + p1) * 33 + k1) * 4096 + abase;
      if ((u & 1) == 0) {
        aB0 = *reinterpret_cast<const half8*>(s);
        aB1 = *reinterpret_cast<const half8*>(s + 1024);
      } else {
        aA0 = *reinterpret_cast<const half8*>(s);
        aA1 = *reinterpret_cast<const half8*>(s + 1024);
      }
    }
    if (u + 2 < 132) STAGE(k2, stg);
    const char* bb = lds + cur * 8192 + (size_t)wn * 4096 + l16;
    const half8 b0 = *reinterpret_cast<const half8*>(bb);
    const half8 b1 = *reinterpret_cast<const half8*>(bb + 1024);
    const half8 b2 = *reinterpret_cast<const half8*>(bb + 2048);
    const half8 b3 = *reinterpret_cast<const half8*>(bb + 3072);
    const half8 a0 = (u & 1) ? aB0 : aA0;
    const half8 a1 = (u & 1) ? aB1 : aA1;
    acc[0][0] = MFMA16(a0, b0, acc[0][0], 0, 0, 0);
    acc[0][1] = MFMA16(a0, b1, acc[0][1], 0, 0, 0);
    acc[0][2] = MFMA16(a0, b2, acc[0][2], 0, 0, 0);
    acc[0][3] = MFMA16(a0, b3, acc[0][3], 0, 0, 0);
    acc[1][0] = MFMA16(a1, b0, acc[1][0], 0, 0, 0);
    acc[1][1] = MFMA16(a1, b1, acc[1][1], 0, 0, 0);
    acc[1][2] = MFMA16(a1, b2, acc[1][2], 0, 0, 0);
    acc[1][3] = MFMA16(a1, b3, acc[1][3], 0, 0, 0);
    if (kt == 32) {  // ---- in-lane fold: top-2 over this panel's 32 candidates ----
      const int cbase = split * 512 + panel * 128 + wm * 64 + 4 * kh;
#pragma unroll
      for (int nb = 0; nb < 4; ++nb) {
        float m1 = qs1[nb], m2 = qs2[nb];
        int i1 = qi1[nb];
#pragma unroll
        for (int ms = 0; ms < 2; ++ms)
#pragma unroll
          for (int r = 0; r < 16; ++r) {
            const float a = acc[ms][nb][r];
            const int ci = cbase + ms * 32 + (r & 3) + 8 * (r >> 2);
            const bool gt = (a > m1) || (a == m1 && ci < i1);
            const float nm2 = gt ? m1 : fmaxf(m2, a);
            m1 = gt ? a : m1;
            i1 = gt ? ci : i1;
            m2 = nm2;
          }
        qs1[nb] = m1; qs2[nb] = m2; qi1[nb] = i1;
      }
#pragma unroll
      for (int ms = 0; ms < 2; ++ms)
#pragma unroll
        for (int nb = 0; nb < 4; ++nb) acc[ms][nb] = (f32x16)0.f;
    }
    if (u < 130) asm volatile("s_waitcnt vmcnt(4)" ::: "memory");
    else         asm volatile("s_waitcnt vmcnt(2)" ::: "memory");
    __builtin_amdgcn_s_barrier();
    ++kt;
    if (kt == 33) { kt = 0; ++panel; }
    cur = (cur == 2) ? 0 : cur + 1;
    stg = (stg == 2) ? 0 : stg + 1;
  }

  // write per-bucket top-2 (score space: s = -2*acc)
  float4* part = (float4*)(ws + WS_PART);
  const int bucket = split * 4 + wm * 2 + kh;
#pragma unroll
  for (int nb = 0; nb < 4; ++nb) {
    const int row = zblk * 256 + wn * 128 + nb * 32 + r31;
    part[(size_t)row * 64 + bucket] =
        make_float4(-2.f * qs1[nb], (float)qi1[nb], -2.f * qs2[nb], 0.f);
  }
}

// ---------------- gather: certify / exact-rescore<=4 / flag ------------------
__global__ __launch_bounds__(64) void gather_finalize(const float* __restrict__ Z,
                                                      const float* __restrict__ Cb,
                                                      char* __restrict__ ws,
                                                      float* __restrict__ zq,
                                                      float* __restrict__ idx_out) {
  const int row = blockIdx.x, l = threadIdx.x;
  const float4 q = ((const float4*)(ws + WS_PART))[(size_t)row * 64 + l];
  float s1 = q.x;
  int i1 = (int)q.y;
#pragma unroll
  for (int off = 1; off <= 32; off <<= 1) {
    const float os = __shfl_xor(s1, off); const int oi = __shfl_xor(i1, off);
    if (os < s1 || (os == s1 && oi < i1)) { s1 = os; i1 = oi; }
  }
  const float zs = ((const float*)(ws + WS_ZSQ))[row];
  const float cmax = __int_as_float(*(const int*)(ws + WS_MAX));
  // sound: 2*[(2^-10+2^-22)*||z||*||c||max + accum + ext] < 4.0e-3*sqrt + 0.05
  const float thr = s1 + 4.0e-3f * sqrtf(zs * cmax) + 0.05f;
  int cnt = (q.x <= thr ? 1 : 0) + (q.z <= thr ? 1 : 0);
  int hide = (q.z <= thr) ? 1 : 0;
#pragma unroll
  for (int off = 1; off <= 32; off <<= 1) {
    cnt += __shfl_xor(cnt, off);
    hide |= __shfl_xor(hide, off);
  }
  if (cnt >= 5 || hide) {
    if (l == 0) {
      const int pos = atomicAdd((int*)(ws + WS_CNT), 1);
      if (pos < Bn) ((int*)(ws + WS_WL))[pos] = row;
    }
    return;  // rescue writes this row
  }
  // exact fp32 rescore of ALL candidates <= thr (<=4, bucket indices are unique)
  const float* csq = (const float*)(ws + WS_CSQ);
  const float4 z0 = *reinterpret_cast<const float4*>(Z + (size_t)row * Dn + l * 8);
  const float4 z1 = *reinterpret_cast<const float4*>(Z + (size_t)row * Dn + l * 8 + 4);
  float mycand = (q.x <= thr) ? q.x : 3e38f;
  const int myid = (int)q.y;
  float best_s = 3e38f;
  int best_i = 0x7fffffff;
  for (int it = 0; it < 4; ++it) {
    float cs_ = mycand;
    int ci_ = myid;
#pragma unroll
    for (int off = 1; off <= 32; off <<= 1) {
      const float os = __shfl_xor(cs_, off); const int oi = __shfl_xor(ci_, off);
      if (os < cs_ || (os == cs_ && oi < ci_)) { cs_ = os; ci_ = oi; }
    }
    if (cs_ > thr) break;  // wave-uniform
    if (myid == ci_) mycand = 3e38f;
    const float4 c0 = *reinterpret_cast<const float4*>(Cb + (size_t)ci_ * Dn + l * 8);
    const float4 c1 = *reinterpret_cast<const float4*>(Cb + (size_t)ci_ * Dn + l * 8 + 4);
    float pa = z0.x * c0.x + z0.y * c0.y + z0.z * c0.z + z0.w * c0.w +
               z1.x * c1.x + z1.y * c1.y + z1.z * c1.z + z1.w * c1.w;
#pragma unroll
    for (int off = 1; off <= 32; off <<= 1) pa += __shfl_xor(pa, off);
    const float se = csq[ci_] - 2.f * pa;
    if (se < best_s || (se == best_s && ci_ < best_i)) { best_s = se; best_i = ci_; }
  }
  const float4 o0 = *reinterpret_cast<const float4*>(Cb + (size_t)best_i * Dn + l * 8);
  const float4 o1 = *reinterpret_cast<const float4*>(Cb + (size_t)best_i * Dn + l * 8 + 4);
  *reinterpret_cast<float4*>(zq + (size_t)row * Dn + l * 8) = o0;
  *reinterpret_cast<float4*>(zq + (size_t)row * Dn + l * 8 + 4) = o1;
  if (l == 0) idx_out[row] = (float)best_i;
}

// ---------------- rescue1: exact fp32 scores for flagged rows ----------------
__global__ __launch_bounds__(256) void rescue1(const float* __restrict__ Z,
                                               const float* __restrict__ Cb,
                                               char* __restrict__ ws) {
  const int cntRaw = *(const int*)(ws + WS_CNT);
  const int cnt = cntRaw > Bn ? Bn : cntRaw;
  if (cnt == 0) return;
  const int tiles_r = (cnt + 63) >> 6;
  const int total = tiles_r * 128;
  const int* wl = (const int*)(ws + WS_WL);
  const float* csq = (const float*)(ws + WS_CSQ);
  float2* p2 = (float2*)(ws + WS_P2);
  __shared__ float As[32][68];
  __shared__ float Bs[32][68];
  __shared__ int wlrows[64];
  const int t = threadIdx.x;
  const int tx = t & 15, ty = t >> 4;
  const int sr = t >> 3, sc = (t & 7) * 4;
  for (int tile = blockIdx.x; tile < total; tile += gridDim.x) {
    const int tr = tile >> 7, tc = tile & 127;
    __syncthreads();
    if (t < 64) {
      const int wi = tr * 64 + t;
      wlrows[t] = wl[wi < cnt ? wi : cnt - 1];
    }
    __syncthreads();
    float acc[4][4] = {};
    for (int k0 = 0; k0 < Dn; k0 += 32) {
#pragma unroll
      for (int rr = 0; rr < 2; ++rr) {
        const int m = sr + rr * 32;
        const float4 v = *reinterpret_cast<const float4*>(Z + (size_t)wlrows[m] * Dn + k0 + sc);
        As[sc + 0][m] = v.x; As[sc + 1][m] = v.y; As[sc + 2][m] = v.z; As[sc + 3][m] = v.w;
        const float4 u = *reinterpret_cast<const float4*>(Cb + (size_t)(tc * 64 + m) * Dn + k0 + sc);
        Bs[sc + 0][m] = u.x; Bs[sc + 1][m] = u.y; Bs[sc + 2][m] = u.z; Bs[sc + 3][m] = u.w;
      }
      __syncthreads();
#pragma unroll
      for (int k = 0; k < 32; ++k) {
        const float4 a = *reinterpret_cast<const float4*>(&As[k][ty * 4]);
        const float4 b = *reinterpret_cast<const float4*>(&Bs[k][tx * 4]);
        acc[0][0] += a.x * b.x; acc[0][1] += a.x * b.y; acc[0][2] += a.x * b.z; acc[0][3] += a.x * b.w;
        acc[1][0] += a.y * b.x; acc[1][1] += a.y * b.y; acc[1][2] += a.y * b.z; acc[1][3] += a.y * b.w;
        acc[2][0] += a.z * b.x; acc[2][1] += a.z * b.y; acc[2][2] += a.z * b.z; acc[2][3] += a.z * b.w;
        acc[3][0] += a.w * b.x; acc[3][1] += a.w * b.y; acc[3][2] += a.w * b.z; acc[3][3] += a.w * b.w;
      }
      __syncthreads();
    }
#pragma unroll
    for (int i = 0; i < 4; ++i) {
      float bsv = 3e38f;
      int bi = 0;
#pragma unroll
      for (int j = 0; j < 4; ++j) {
        const int n = tc * 64 + tx * 4 + j;
        const float s = csq[n] - 2.f * acc[i][j];
        if (s < bsv || (s == bsv && n < bi)) { bsv = s; bi = n; }
      }
#pragma unroll
      for (int off = 1; off <= 8; off <<= 1) {
        const float os = __shfl_xor(bsv, off); const int oi = __shfl_xor(bi, off);
        if (os < bsv || (os == bsv && oi < bi)) { bsv = os; bi = oi; }
      }
      if (tx == 0) p2[(size_t)(tr * 64 + ty * 4 + i) * 128 + tc] = make_float2(bsv, (float)bi);
    }
  }
}

// ---------------- rescue2: combine col-tile minima + write -------------------
__global__ __launch_bounds__(64) void rescue2(const float* __restrict__ Cb,
                                              char* __restrict__ ws,
                                              float* __restrict__ zq,
                                              float* __restrict__ idx_out) {
  const int cntRaw = *(const int*)(ws + WS_CNT);
  const int cnt = cntRaw > Bn ? Bn : cntRaw;
  const int* wl = (const int*)(ws + WS_WL);
  const float2* p2 = (const float2*)(ws + WS_P2);
  const int l = threadIdx.x;
  for (int rr = blockIdx.x; rr < cnt; rr += gridDim.x) {
    const int row = wl[rr];
    const float2 e1 = p2[(size_t)rr * 128 + l];
    const float2 e2 = p2[(size_t)rr * 128 + 64 + l];
    float bs_ = e1.x;
    int bi_ = (int)e1.y;
    if (e2.x < bs_ || (e2.x == bs_ && (int)e2.y < bi_)) { bs_ = e2.x; bi_ = (int)e2.y; }
#pragma unroll
    for (int off = 1; off <= 32; off <<= 1) {
      const float os = __shfl_xor(bs_, off); const int oi = __shfl_xor(bi_, off);
      if (os < bs_ || (os == bs_ && oi < bi_)) { bs_ = os; bi_ = oi; }
    }
    const float4 c0 = *reinterpret_cast<const float4*>(Cb + (size_t)bi_ * Dn + l * 8);
    const float4 c1 = *reinterpret_cast<const float4*>(Cb + (size_t)bi_ * Dn + l * 8 + 4);
    *reinterpret_cast<float4*>(zq + (size_t)row * Dn + l * 8) = c0;
    *reinterpret_cast<float4*>(zq + (size_t)row * Dn + l * 8 + 4) = c1;
    if (l == 0) idx_out[row] = (float)bi_;
  }
}

extern "C" void kernel_launch(void* const* d_in, const int* in_sizes, int n_in,
                              void* d_out, int out_size, void* d_ws, size_t ws_size,
                              hipStream_t stream) {
  const float* Z = (const float*)d_in[0];  // [B, D]
  const float* C = (const float*)d_in[1];  // [K, D]
  float* out = (float*)d_out;              // [B*D] z_q then [B] indices
  char* ws = (char*)d_ws;                  // ~28.6MB

  prep_kernel<<<4096, 256, 0, stream>>>(Z, C, ws);
  vq_pass1<<<512, 256, 0, stream>>>(ws);
  gather_finalize<<<Bn, 64, 0, stream>>>(Z, C, ws, out, out + (size_t)Bn * Dn);
  rescue1<<<512, 256, 0, stream>>>(Z, C, ws);
  rescue2<<<256, 64, 0, stream>>>(C, ws, out, out + (size_t)Bn * Dn);
}